// Round 1
// baseline (218.455 us; speedup 1.0000x reference)
//
#include <hip/hip_runtime.h>
#include <math.h>

#define BATCH 64
#define H 80
#define W 80
#define C 80
#define CP4 84
#define TOPK 100
#define THRESH 2.5f
#define NBINS 4096
#define COLLECT_CAP 2048
#define SPLITS 4
#define RPT (H / SPLITS)            // 20 rows per block
#define JT 16                       // j-pixels per block tile
#define NJB (W / JT)                // 5 tiles across width
#define BPB (SPLITS * NJB)          // 20 blocks per batch
#define SEGCAP 800                  // candidate slots per block segment
#define BLK 320                     // 5 waves: 16 j-lanes x 20 c4-groups
#define PXF4 (CP4 / 4)              // 21 float4 per pixel record
#define ROWF4 ((JT + 2) * PXF4)     // 378 float4 per staged row (16 px + 2 halo)

// float -> monotonic sortable uint (ascending key == ascending float)
__device__ __forceinline__ unsigned int f2key(float f) {
    unsigned int u = __float_as_uint(f);
    return (u & 0x80000000u) ? ~u : (u | 0x80000000u);
}
__device__ __forceinline__ float key2f(unsigned int k) {
    unsigned int u = (k & 0x80000000u) ? (k & 0x7FFFFFFFu) : ~k;
    return __uint_as_float(u);
}

union F4 { float4 v; float a[4]; };

__device__ __forceinline__ F4 f4max(F4 x, F4 y) {
    F4 r;
    r.a[0] = fmaxf(x.a[0], y.a[0]);
    r.a[1] = fmaxf(x.a[1], y.a[1]);
    r.a[2] = fmaxf(x.a[2], y.a[2]);
    r.a[3] = fmaxf(x.a[3], y.a[3]);
    return r;
}

// Stage1 v2: fully-coalesced row staging.
// Each block owns (batch b, row-split s, 16-pixel j-tile jb).
// Per row: the block loads the contiguous 18-px * 84-ch span (378 float4,
// lane-linear => 1024 contiguous B per wave instruction) into an LDS ring
// buffer (3 rows). Loads for row i+2 are issued into registers while row i+1
// is written/consumed (issue-early/write-late), so HBM latency hides under
// the barrier+compute of the current row. Vertical 3-max stays a rolling
// register scan; horizontal 3-max is 3 ds_read_b128 from LDS (2-way bank
// aliasing only => free). No divergent halo loads, no ds_bpermute chain.
__global__ __launch_bounds__(BLK) void stage1_kernel(const float* __restrict__ y,
                                                     unsigned int* __restrict__ cnt,
                                                     uint2* __restrict__ cand,
                                                     int segcap) {
    const int jb = blockIdx.x % NJB;
    const int s  = (blockIdx.x / NJB) % SPLITS;
    const int b  = blockIdx.x / BPB;
    const int t  = threadIdx.x;
    const int lane = t & 63;
    const int wv   = t >> 6;
    const int jl   = lane & (JT - 1);      // j within tile
    const int cg   = lane >> 4;            // c4-subgroup within wave
    const int cidx = wv * 4 + cg;          // float4 index within pixel, 0..19 (ch 0..79)
    const int j0   = jb * JT;
    const int i0   = s * RPT;

    __shared__ float4 rowbuf[3][ROWF4];    // 18,144 B ring of staged rows
    __shared__ uint2 sbuf[1024];
    __shared__ unsigned int scount;
    if (t == 0) scount = 0u;

    // loader constants: float4 q covers pixel q/21, sub-record q%21
    const int q1  = t + BLK;                       // 320..639, active if < 378
    const int px0 = t / 21,  r0 = t - px0 * 21;
    const int px1 = q1 / 21, r1 = q1 - px1 * 21;
    const int gj0 = j0 - 1 + px0;
    const int gj1 = j0 - 1 + px1;
    const bool a0 = (gj0 >= 0 && gj0 < W);
    const bool a1 = (q1 < ROWF4) && (gj1 >= 0 && gj1 < W);

    const float* __restrict__ yb = y + (size_t)b * (H * W * CP4);

    F4 NEG;
    NEG.a[0] = NEG.a[1] = NEG.a[2] = NEG.a[3] = -INFINITY;

    float4 h0, h1;                                  // in-flight staging regs
    auto issue_row = [&](int i) {
        const bool iv = (i >= 0 && i < H);
        const float* rp = yb + (size_t)i * (W * CP4);
        h0 = NEG.v; h1 = NEG.v;
        if (iv && a0) h0 = *(const float4*)(rp + gj0 * CP4 + r0 * 4);
        if (iv && a1) h1 = *(const float4*)(rp + gj1 * CP4 + r1 * 4);
    };
    auto write_row = [&](int buf) {
        rowbuf[buf][t] = h0;
        if (q1 < ROWF4) rowbuf[buf][q1] = h1;
    };
    auto horiz = [&](int buf, F4& rm, F4& mid) {
        F4 l, c, r;
        l.v = rowbuf[buf][(jl + 0) * PXF4 + cidx];  // global j-1
        c.v = rowbuf[buf][(jl + 1) * PXF4 + cidx];  // global j
        r.v = rowbuf[buf][(jl + 2) * PXF4 + cidx];  // global j+1
        rm = f4max(f4max(l, r), c);
        mid = c;
    };

    // prologue: rows i0-1, i0 staged; row i0+1 in flight
    issue_row(i0 - 1); write_row(0);
    issue_row(i0);     write_row(1);
    issue_row(i0 + 1);
    __syncthreads();

    F4 rm_p, rm_c, rm_n, mid_c, mid_n, dum;
    horiz(0, rm_p, dum);
    horiz(1, rm_c, mid_c);

    int wb = 2;                                     // ring write index
    for (int k = 0; k < RPT; ++k) {
        const int i = i0 + k;
        __syncthreads();                            // all reads of rowbuf[wb] (2 iters ago) done
        write_row(wb);                              // row i+1 -> LDS
        if (k + 1 < RPT) issue_row(i + 2);          // prefetch row i+2 into regs
        __syncthreads();                            // row i+1 visible
        horiz(wb, rm_n, mid_n);

        const F4 m = f4max(f4max(rm_p, rm_c), rm_n);
        #pragma unroll
        for (int q = 0; q < 4; ++q) {
            const float cv = mid_c.a[q];
            if (cv > THRESH && cv == m.a[q]) {
                const unsigned int p = atomicAdd(&scount, 1u);
                if (p < 1024u) {
                    const unsigned int idx = (unsigned int)((i * W + (j0 + jl)) * C + (cidx * 4 + q));
                    sbuf[p] = make_uint2(f2key(cv), idx);
                }
            }
        }
        rm_p = rm_c; rm_c = rm_n; mid_c = mid_n;
        wb = (wb == 2) ? 0 : wb + 1;
    }
    __syncthreads();

    // per-block private segment: no global atomics, no zero pass needed
    const unsigned int mcnt = min(scount, (unsigned int)segcap);
    const int seg = b * BPB + s * NJB + jb;
    if (t == 0) cnt[seg] = mcnt;
    uint2* __restrict__ segp = cand + (size_t)seg * segcap;
    for (unsigned int q = t; q < mcnt; q += BLK) segp[q] = sbuf[q];
}

// One block per batch: radix-histogram select of top-K among candidate
// segments, exact stable rank of survivors, compute final outputs.
__global__ __launch_bounds__(256) void stage2_kernel(const float* __restrict__ y,
                                                     const unsigned int* __restrict__ cnt,
                                                     const uint2* __restrict__ cand,
                                                     int segcap,
                                                     float* __restrict__ out) {
    const int b = blockIdx.x;
    const int t = threadIdx.x;

    __shared__ unsigned int hist[NBINS];
    __shared__ uint2 coll[COLLECT_CAP];
    __shared__ unsigned int suf[256];
    __shared__ unsigned int scnt[BPB];
    __shared__ unsigned int sT, sM;

    if (t < BPB) scnt[t] = min(cnt[b * BPB + t], (unsigned int)segcap);
    for (int q = t; q < NBINS; q += 256) hist[q] = 0u;
    if (t == 0) sM = 0u;
    __syncthreads();

    for (int seg = 0; seg < BPB; ++seg) {
        const unsigned int cs = scnt[seg];
        const uint2* __restrict__ cb = cand + (size_t)(b * BPB + seg) * segcap;
        for (unsigned int q = t; q < cs; q += 256u)
            atomicAdd(&hist[cb[q].x >> 20], 1u);
    }
    __syncthreads();

    // per-thread chunk sum (16 bins each), then parallel suffix scan
    unsigned int sch = 0;
    #pragma unroll
    for (int q = 0; q < 16; ++q) sch += hist[t * 16 + q];
    suf[t] = sch;
    __syncthreads();
    for (int off = 1; off < 256; off <<= 1) {
        const unsigned int v = suf[t] + ((t + off < 256) ? suf[t + off] : 0u);
        __syncthreads();
        suf[t] = v;
        __syncthreads();
    }
    // threshold bin T: smallest bin with suffix-count >= TOPK
    if (t == 0 && suf[0] < (unsigned int)TOPK) sT = 0u;   // fewer than K candidates: keep all
    if (suf[t] >= (unsigned int)TOPK && (t == 255 || suf[t + 1] < (unsigned int)TOPK)) {
        unsigned int cum = (t == 255) ? 0u : suf[t + 1];
        unsigned int T = (unsigned int)(t * 16);
        for (int bin = t * 16 + 15; bin >= t * 16; --bin) {
            cum += hist[bin];
            if (cum >= (unsigned int)TOPK) { T = (unsigned int)bin; break; }
        }
        sT = T;
    }
    __syncthreads();

    const unsigned int T = sT;
    for (int seg = 0; seg < BPB; ++seg) {
        const unsigned int cs = scnt[seg];
        const uint2* __restrict__ cb = cand + (size_t)(b * BPB + seg) * segcap;
        for (unsigned int q = t; q < cs; q += 256u) {
            const uint2 e = cb[q];
            if ((e.x >> 20) >= T) {
                const unsigned int p = atomicAdd(&sM, 1u);
                if (p < (unsigned int)COLLECT_CAP) coll[p] = e;
            }
        }
    }
    __syncthreads();

    const unsigned int M = min(sM, (unsigned int)COLLECT_CAP);

    // exact stable rank: score desc, index asc (matches stable argsort(-score))
    for (unsigned int q = t; q < M; q += 256u) {
        const uint2 e = coll[q];
        unsigned int r = 0;
        for (unsigned int jx = 0; jx < M; ++jx) {
            const uint2 o = coll[jx];
            r += (o.x > e.x) || (o.x == e.x && o.y < e.y);
        }
        if (r < (unsigned int)TOPK) {
            const float score = key2f(e.x);
            const unsigned int idx = e.y;
            const unsigned int c  = idx % C;
            const unsigned int j2 = (idx / C) % W;
            const unsigned int i2 = idx / (C * W);
            const float* __restrict__ p = y + ((size_t)(b * H + i2) * W + j2) * CP4;
            const float w0 = expf(p[C + 0]) - 1.0f;
            const float w1 = expf(p[C + 1]) - 1.0f;
            const float b0 = p[C + 2];
            const float b1 = p[C + 3];
            const int o1 = b * TOPK + r;
            out[o1] = score;                                              // score_k
            out[BATCH * TOPK + o1] = (float)c;                            // k
            out[2 * BATCH * TOPK + 2 * o1 + 0] = 4.0f * (float)j2 + b0;   // centers x
            out[2 * BATCH * TOPK + 2 * o1 + 1] = 4.0f * (float)i2 + b1;   // centers y
            out[4 * BATCH * TOPK + 2 * o1 + 0] = 4.0f * w0;               // wh x
            out[4 * BATCH * TOPK + 2 * o1 + 1] = 4.0f * w1;               // wh y
        }
    }

    for (unsigned int q = M + t; q < (unsigned int)TOPK; q += 256u) {
        const int o1 = b * TOPK + q;
        out[o1] = 0.0f;
        out[BATCH * TOPK + o1] = 0.0f;
        out[2 * BATCH * TOPK + 2 * o1 + 0] = 0.0f;
        out[2 * BATCH * TOPK + 2 * o1 + 1] = 0.0f;
        out[4 * BATCH * TOPK + 2 * o1 + 0] = 0.0f;
        out[4 * BATCH * TOPK + 2 * o1 + 1] = 0.0f;
    }
}

extern "C" void kernel_launch(void* const* d_in, const int* in_sizes, int n_in,
                              void* d_out, int out_size, void* d_ws, size_t ws_size,
                              hipStream_t stream) {
    const float* y = (const float*)d_in[0];
    float* out = (float*)d_out;

    unsigned int* cnt = (unsigned int*)d_ws;                 // BATCH*BPB counts
    uint2* cand = (uint2*)((char*)d_ws + 8192);

    int segcap = SEGCAP;
    const size_t need = 8192 + (size_t)BATCH * BPB * (size_t)SEGCAP * sizeof(uint2);
    if (ws_size < need && ws_size > 8192 + (size_t)BATCH * BPB * sizeof(uint2)) {
        segcap = (int)((ws_size - 8192) / ((size_t)BATCH * BPB * sizeof(uint2)));
    }

    stage1_kernel<<<BATCH * BPB, BLK, 0, stream>>>(y, cnt, cand, segcap);
    stage2_kernel<<<BATCH, 256, 0, stream>>>(y, cnt, cand, segcap, out);
}

// Round 2
// 216.849 us; speedup vs baseline: 1.0074x; 1.0074x over previous
//
#include <hip/hip_runtime.h>
#include <math.h>

#define BATCH 64
#define H 80
#define W 80
#define C 80
#define CP4 84
#define TOPK 100
#define THRESH 2.5f
#define NBINS 4096
#define COLLECT_CAP 2048
#define SPLITS 4
#define RPT (H / SPLITS)            // 20 rows per block
#define JT 16                       // j-pixels per block tile
#define NJB (W / JT)                // 5 tiles across width
#define BPB (SPLITS * NJB)          // 20 blocks per batch
#define SEGCAP 800                  // candidate slots per block segment
#define SBUF 512                    // LDS candidate buffer (expected ~155/block)
#define BLK 320                     // 5 waves: 16 j-lanes x 20 c4-groups
#define PXF4 (CP4 / 4)              // 21 float4 per pixel record (odd => conflict-free LDS stride)
#define ROWF4 ((JT + 2) * PXF4)     // 378 float4 per staged row (16 px + 2 halo)

// float -> monotonic sortable uint (ascending key == ascending float)
__device__ __forceinline__ unsigned int f2key(float f) {
    unsigned int u = __float_as_uint(f);
    return (u & 0x80000000u) ? ~u : (u | 0x80000000u);
}
__device__ __forceinline__ float key2f(unsigned int k) {
    unsigned int u = (k & 0x80000000u) ? (k & 0x7FFFFFFFu) : ~k;
    return __uint_as_float(u);
}

union F4 { float4 v; float a[4]; };

__device__ __forceinline__ F4 f4max(F4 x, F4 y) {
    F4 r;
    r.a[0] = fmaxf(x.a[0], y.a[0]);
    r.a[1] = fmaxf(x.a[1], y.a[1]);
    r.a[2] = fmaxf(x.a[2], y.a[2]);
    r.a[3] = fmaxf(x.a[3], y.a[3]);
    return r;
}

// Stage1 v3: coalesced row staging, 4-slot LDS ring, ONE barrier per row.
// Ring hazard analysis (row m staged in slot m&3, iter k horiz-reads slot
// (k+2)&3, writes slot (k+3)&3): a slot being written was last read at
// iter k-3, three barriers earlier; data read at iter k was written at
// iter k-1, one barrier earlier. So a single end-of-iteration barrier
// provides all ordering. Global loads for row m=k+4 are issued at iter k
// and consumed (LDS write) at iter k+1 => one full compute+barrier phase
// of latency hiding. Prologue issues all 4 initial row loads before any
// dependent LDS write.
__global__ __launch_bounds__(BLK) void stage1_kernel(const float* __restrict__ y,
                                                     unsigned int* __restrict__ cnt,
                                                     uint2* __restrict__ cand,
                                                     int segcap) {
    const int jb = blockIdx.x % NJB;
    const int s  = (blockIdx.x / NJB) % SPLITS;
    const int b  = blockIdx.x / BPB;
    const int t  = threadIdx.x;
    const int lane = t & 63;
    const int wv   = t >> 6;
    const int jl   = lane & (JT - 1);      // j within tile
    const int cg   = lane >> 4;            // c4-subgroup within wave
    const int cidx = wv * 4 + cg;          // float4 index within pixel, 0..19 (ch 0..79)
    const int j0   = jb * JT;
    const int i0   = s * RPT;

    __shared__ float4 rowbuf[4][ROWF4];    // 24,192 B ring
    __shared__ uint2 sbuf[SBUF];
    __shared__ unsigned int scount;
    if (t == 0) scount = 0u;

    // loader constants: float4 q covers pixel q/21, sub-record q%21
    const int q1  = t + BLK;                       // 320..639, active if < 378
    const int px0 = t / 21,  r0 = t - px0 * 21;
    const int px1 = q1 / 21, r1 = q1 - px1 * 21;
    const int gj0 = j0 - 1 + px0;
    const int gj1 = j0 - 1 + px1;
    const bool a0 = (gj0 >= 0 && gj0 < W);
    const bool a1 = (q1 < ROWF4) && (gj1 >= 0 && gj1 < W);

    const float* __restrict__ yb = y + (size_t)b * (H * W * CP4);

    F4 NEG;
    NEG.a[0] = NEG.a[1] = NEG.a[2] = NEG.a[3] = -INFINITY;

    auto issue_row = [&](int i, float4& h0, float4& h1) {
        const bool iv = ((unsigned)i < (unsigned)H);
        const float* rp = yb + (size_t)i * (W * CP4);
        h0 = NEG.v; h1 = NEG.v;
        if (iv && a0) h0 = *(const float4*)(rp + gj0 * CP4 + r0 * 4);
        if (iv && a1) h1 = *(const float4*)(rp + gj1 * CP4 + r1 * 4);
    };
    auto horiz = [&](int buf, F4& rm, F4& mid) {
        F4 l, c, r;
        l.v = rowbuf[buf][(jl + 0) * PXF4 + cidx];  // global j-1
        c.v = rowbuf[buf][(jl + 1) * PXF4 + cidx];  // global j
        r.v = rowbuf[buf][(jl + 2) * PXF4 + cidx];  // global j+1
        rm = f4max(f4max(l, r), c);
        mid = c;
    };

    // prologue: issue rows m=0..3 (i0-1 .. i0+2) before any dependent write
    float4 p00, p01, p10, p11, p20, p21, h0, h1;
    issue_row(i0 - 1, p00, p01);
    issue_row(i0 + 0, p10, p11);
    issue_row(i0 + 1, p20, p21);
    issue_row(i0 + 2, h0, h1);                      // row m=3 stays in regs
    rowbuf[0][t] = p00; if (q1 < ROWF4) rowbuf[0][q1] = p01;
    rowbuf[1][t] = p10; if (q1 < ROWF4) rowbuf[1][q1] = p11;
    rowbuf[2][t] = p20; if (q1 < ROWF4) rowbuf[2][q1] = p21;
    __syncthreads();

    F4 rm_p, rm_c, rm_n, mid_c, mid_n, dum;
    horiz(0, rm_p, dum);
    horiz(1, rm_c, mid_c);

    for (int k = 0; k < RPT; ++k) {
        const int i = i0 + k;
        horiz((k + 2) & 3, rm_n, mid_n);            // row i+1 (slot written iter k-1)
        if (k <= RPT - 2) {                         // stage row m=k+3 (i+2)
            const int wb = (k + 3) & 3;
            rowbuf[wb][t] = h0;
            if (q1 < ROWF4) rowbuf[wb][q1] = h1;
        }
        if (k <= RPT - 3) issue_row(i0 + k + 3, h0, h1);  // prefetch row m=k+4

        const F4 m = f4max(f4max(rm_p, rm_c), rm_n);
        #pragma unroll
        for (int q = 0; q < 4; ++q) {
            const float cv = mid_c.a[q];
            if (cv > THRESH && cv == m.a[q]) {
                const unsigned int p = atomicAdd(&scount, 1u);
                if (p < (unsigned int)SBUF) {
                    const unsigned int idx = (unsigned int)((i * W + (j0 + jl)) * C + (cidx * 4 + q));
                    sbuf[p] = make_uint2(f2key(cv), idx);
                }
            }
        }
        rm_p = rm_c; rm_c = rm_n; mid_c = mid_n;
        __syncthreads();
    }

    // per-block private segment: no global atomics, no zero pass needed
    const unsigned int mcnt = min(min(scount, (unsigned int)SBUF), (unsigned int)segcap);
    const int seg = b * BPB + s * NJB + jb;
    if (t == 0) cnt[seg] = mcnt;
    uint2* __restrict__ segp = cand + (size_t)seg * segcap;
    for (unsigned int q = t; q < mcnt; q += BLK) segp[q] = sbuf[q];
}

// One block per batch: radix-histogram select of top-K among candidate
// segments, exact stable rank of survivors, compute final outputs.
__global__ __launch_bounds__(256) void stage2_kernel(const float* __restrict__ y,
                                                     const unsigned int* __restrict__ cnt,
                                                     const uint2* __restrict__ cand,
                                                     int segcap,
                                                     float* __restrict__ out) {
    const int b = blockIdx.x;
    const int t = threadIdx.x;

    __shared__ unsigned int hist[NBINS];
    __shared__ uint2 coll[COLLECT_CAP];
    __shared__ unsigned int suf[256];
    __shared__ unsigned int scnt[BPB];
    __shared__ unsigned int sT, sM;

    if (t < BPB) scnt[t] = min(cnt[b * BPB + t], (unsigned int)segcap);
    for (int q = t; q < NBINS; q += 256) hist[q] = 0u;
    if (t == 0) sM = 0u;
    __syncthreads();

    for (int seg = 0; seg < BPB; ++seg) {
        const unsigned int cs = scnt[seg];
        const uint2* __restrict__ cb = cand + (size_t)(b * BPB + seg) * segcap;
        for (unsigned int q = t; q < cs; q += 256u)
            atomicAdd(&hist[cb[q].x >> 20], 1u);
    }
    __syncthreads();

    // per-thread chunk sum (16 bins each), then parallel suffix scan
    unsigned int sch = 0;
    #pragma unroll
    for (int q = 0; q < 16; ++q) sch += hist[t * 16 + q];
    suf[t] = sch;
    __syncthreads();
    for (int off = 1; off < 256; off <<= 1) {
        const unsigned int v = suf[t] + ((t + off < 256) ? suf[t + off] : 0u);
        __syncthreads();
        suf[t] = v;
        __syncthreads();
    }
    // threshold bin T: smallest bin with suffix-count >= TOPK
    if (t == 0 && suf[0] < (unsigned int)TOPK) sT = 0u;   // fewer than K candidates: keep all
    if (suf[t] >= (unsigned int)TOPK && (t == 255 || suf[t + 1] < (unsigned int)TOPK)) {
        unsigned int cum = (t == 255) ? 0u : suf[t + 1];
        unsigned int T = (unsigned int)(t * 16);
        for (int bin = t * 16 + 15; bin >= t * 16; --bin) {
            cum += hist[bin];
            if (cum >= (unsigned int)TOPK) { T = (unsigned int)bin; break; }
        }
        sT = T;
    }
    __syncthreads();

    const unsigned int T = sT;
    for (int seg = 0; seg < BPB; ++seg) {
        const unsigned int cs = scnt[seg];
        const uint2* __restrict__ cb = cand + (size_t)(b * BPB + seg) * segcap;
        for (unsigned int q = t; q < cs; q += 256u) {
            const uint2 e = cb[q];
            if ((e.x >> 20) >= T) {
                const unsigned int p = atomicAdd(&sM, 1u);
                if (p < (unsigned int)COLLECT_CAP) coll[p] = e;
            }
        }
    }
    __syncthreads();

    const unsigned int M = min(sM, (unsigned int)COLLECT_CAP);

    // exact stable rank: score desc, index asc (matches stable argsort(-score))
    for (unsigned int q = t; q < M; q += 256u) {
        const uint2 e = coll[q];
        unsigned int r = 0;
        for (unsigned int jx = 0; jx < M; ++jx) {
            const uint2 o = coll[jx];
            r += (o.x > e.x) || (o.x == e.x && o.y < e.y);
        }
        if (r < (unsigned int)TOPK) {
            const float score = key2f(e.x);
            const unsigned int idx = e.y;
            const unsigned int c  = idx % C;
            const unsigned int j2 = (idx / C) % W;
            const unsigned int i2 = idx / (C * W);
            const float* __restrict__ p = y + ((size_t)(b * H + i2) * W + j2) * CP4;
            const float w0 = expf(p[C + 0]) - 1.0f;
            const float w1 = expf(p[C + 1]) - 1.0f;
            const float b0 = p[C + 2];
            const float b1 = p[C + 3];
            const int o1 = b * TOPK + r;
            out[o1] = score;                                              // score_k
            out[BATCH * TOPK + o1] = (float)c;                            // k
            out[2 * BATCH * TOPK + 2 * o1 + 0] = 4.0f * (float)j2 + b0;   // centers x
            out[2 * BATCH * TOPK + 2 * o1 + 1] = 4.0f * (float)i2 + b1;   // centers y
            out[4 * BATCH * TOPK + 2 * o1 + 0] = 4.0f * w0;               // wh x
            out[4 * BATCH * TOPK + 2 * o1 + 1] = 4.0f * w1;               // wh y
        }
    }

    for (unsigned int q = M + t; q < (unsigned int)TOPK; q += 256u) {
        const int o1 = b * TOPK + q;
        out[o1] = 0.0f;
        out[BATCH * TOPK + o1] = 0.0f;
        out[2 * BATCH * TOPK + 2 * o1 + 0] = 0.0f;
        out[2 * BATCH * TOPK + 2 * o1 + 1] = 0.0f;
        out[4 * BATCH * TOPK + 2 * o1 + 0] = 0.0f;
        out[4 * BATCH * TOPK + 2 * o1 + 1] = 0.0f;
    }
}

extern "C" void kernel_launch(void* const* d_in, const int* in_sizes, int n_in,
                              void* d_out, int out_size, void* d_ws, size_t ws_size,
                              hipStream_t stream) {
    const float* y = (const float*)d_in[0];
    float* out = (float*)d_out;

    unsigned int* cnt = (unsigned int*)d_ws;                 // BATCH*BPB counts
    uint2* cand = (uint2*)((char*)d_ws + 8192);

    int segcap = SEGCAP;
    const size_t need = 8192 + (size_t)BATCH * BPB * (size_t)SEGCAP * sizeof(uint2);
    if (ws_size < need && ws_size > 8192 + (size_t)BATCH * BPB * sizeof(uint2)) {
        segcap = (int)((ws_size - 8192) / ((size_t)BATCH * BPB * sizeof(uint2)));
    }

    stage1_kernel<<<BATCH * BPB, BLK, 0, stream>>>(y, cnt, cand, segcap);
    stage2_kernel<<<BATCH, 256, 0, stream>>>(y, cnt, cand, segcap, out);
}